// Round 2
// baseline (180.221 us; speedup 1.0000x reference)
//
#include <hip/hip_runtime.h>
#include <math.h>

// ComplexEMA fused single-kernel version (R4 = R3 + scan-region register relief).
// y[b,d,t] = Re(sum_n gam_dn * h_dn[t]) + omega_d * x[b,d,t]
// h[t] = q*h[t-1] + p*x[t];  substitution u = h/p:  u' = q*u + x, gam' = p*gam.
//
// One block (128 threads) per (b,d) row. Each thread owns a 32-step chunk and
// keeps its x in registers for both recurrence phases (x read ONCE from HBM).
// Phase 1: local chunk recurrence from zero -> chunk end-state F (16 complex).
// Scan:    7-step Hillis-Steele over the 128 chunk states in LDS (A = q^32),
//          XOR-swizzled float4 layout (row stride 128B would be a 32-way
//          bank conflict otherwise -- guide §6 G4).
// Phase 3: re-run chunk from exclusive prefix, emit y with burst stores.
// R4 changes vs R3:
//  - qx/qy (and g) are NOT kept live across the scan; rebuilt from LDS after.
//    Peak scan liveness drops ~230 -> ~165 VGPR (spill-proofing the barrier-
//    dense region under the __launch_bounds__(128,2) 256-VGPR budget).
//  - phase-1 first step peeled (u==0 -> u[n]=(x0,0)), -32 packed FMAs/thread.

constexpr int kD = 2048, kN = 16, kB = 2, kL = 4096;
constexpr int kT  = 128;            // threads (= chunks) per row
constexpr int kCH = kL / kT;        // 32 timesteps per thread
constexpr float kSCALE = 0.25f;     // sqrt(1/16)

typedef float v2 __attribute__((ext_vector_type(2)));

static __device__ __forceinline__ v2 mkv2(float a, float b) {
    v2 r; r.x = a; r.y = b; return r;
}

static __device__ __forceinline__ v2 v2fma(v2 a, v2 b, v2 c) {
#if __has_builtin(__builtin_elementwise_fma)
    return __builtin_elementwise_fma(a, b, c);
#else
    v2 r;
    r.x = __builtin_fmaf(a.x, b.x, c.x);
    r.y = __builtin_fmaf(a.y, b.y, c.y);
    return r;
#endif
}

__global__ __launch_bounds__(kT, 2) void fused_kernel(
    const float* __restrict__ x,     const float* __restrict__ alpha,
    const float* __restrict__ delta, const float* __restrict__ theta,
    const float* __restrict__ gamma, const float* __restrict__ omega,
    float* __restrict__ y,           float* __restrict__ hout)
{
    // scan buffer: 128 rows x 8 float4 (32 floats = 16 complex), 16 KB.
    __shared__ float4 scan4[kT * 8];
    __shared__ float cqr[kN], cqi[kN], cgr[kN], cgi[kN], cp[kN];

    const int row = blockIdx.x;          // b*kD + d
    const int d   = row & (kD - 1);
    const int tid = threadIdx.x;

    // --- burst-load this thread's 32 x samples (8 back-to-back dwordx4 =
    //     128 B/lane; full-line coverage). Issued first so HBM latency hides
    //     under the coefficient transcendentals.
    const float4* xp = (const float4*)(x + (size_t)row * kL + (size_t)tid * kCH);
    float xs[kCH];
#pragma unroll
    for (int k = 0; k < 8; k++) {
        float4 t = xp[k];
        xs[4*k+0] = t.x; xs[4*k+1] = t.y; xs[4*k+2] = t.z; xs[4*k+3] = t.w;
    }

    // --- coefficients (threads 0..15, one n each)
    if (tid < kN) {
        int n = tid, i = d * kN + n;
        float p  = 1.0f / (1.0f + expf(-alpha[i]));
        float dd = 1.0f / (1.0f + expf(-delta[i]));
        float th = 1.0f / (1.0f + expf(-theta[d]));
        float phi = (float)(n + 1) * th * 0.39269908169872414f;  // 2*pi/16
        float r = 1.0f - p * dd;
        float s, c;
        sincosf(phi, &s, &c);
        cqr[n] = r * c;
        cqi[n] = r * s;
        cgr[n] = p * kSCALE * gamma[2 * i];
        cgi[n] = -(p * kSCALE * gamma[2 * i + 1]);
        cp[n]  = p;
    }
    __syncthreads();

    v2 qx[kN], qy[kN], u[kN];
#pragma unroll
    for (int n = 0; n < kN; n++) {
        qx[n] = mkv2(cqr[n],  cqr[n]);
        qy[n] = mkv2(-cqi[n], cqi[n]);
    }

    // --- phase 1: local recurrence from zero init; u ends as chunk state F.
    //     First step peeled: u = q*0 + x0 = (x0, 0).
#pragma unroll
    for (int n = 0; n < kN; n++) u[n] = mkv2(xs[0], 0.0f);
#pragma unroll
    for (int j = 1; j < kCH; j++) {
        v2 xv = mkv2(xs[j], 0.0f);
#pragma unroll
        for (int n = 0; n < kN; n++) {
            v2 a = v2fma(qx[n], u[n], xv);
            u[n] = v2fma(qy[n], mkv2(u[n].y, u[n].x), a);
        }
    }

    // --- m = q^kCH = q^32 via 5 complex squarings
    v2 m[kN];
#pragma unroll
    for (int n = 0; n < kN; n++) m[n] = mkv2(cqr[n], cqi[n]);
#pragma unroll
    for (int k = 0; k < 5; k++) {
#pragma unroll
        for (int n = 0; n < kN; n++) {
            float mr = m[n].x, mi = m[n].y;
            m[n] = mkv2(__builtin_fmaf(mr, mr, -(mi * mi)), 2.0f * mr * mi);
        }
    }

    // --- Hillis-Steele inclusive scan over the 128 chunk states.
    //     LDS rows are 128 B apart -> XOR-swizzle the float4 index with
    //     (row & 7) so a wave's lanes tile the 32 banks evenly.
    const int sw = tid & 7;
#pragma unroll
    for (int k = 0; k < 8; k++)
        scan4[tid * 8 + (k ^ sw)] =
            make_float4(u[2*k].x, u[2*k].y, u[2*k+1].x, u[2*k+1].y);
    __syncthreads();

    for (int s = 1; s < kT; s <<= 1) {
        const bool act = (tid >= s);
        if (act) {
            int r = tid - s, rsw = r & 7;
            v2 pv[kN];
#pragma unroll
            for (int k = 0; k < 8; k++) {
                float4 t = scan4[r * 8 + (k ^ rsw)];
                pv[2*k]   = mkv2(t.x, t.y);
                pv[2*k+1] = mkv2(t.z, t.w);
            }
            // u += m (complex*) pv   (m = A^s at step s)
#pragma unroll
            for (int n = 0; n < kN; n++) {
                float pr = pv[n].x, pi = pv[n].y;
                u[n].x = __builtin_fmaf(m[n].x, pr,
                         __builtin_fmaf(-m[n].y, pi, u[n].x));
                u[n].y = __builtin_fmaf(m[n].x, pi,
                         __builtin_fmaf( m[n].y, pr, u[n].y));
            }
        }
        __syncthreads();                 // all reads done before overwrite
        if (act) {
#pragma unroll
            for (int k = 0; k < 8; k++)
                scan4[tid * 8 + (k ^ sw)] =
                    make_float4(u[2*k].x, u[2*k].y, u[2*k+1].x, u[2*k+1].y);
        }
        // m = m^2 (uniform, all threads)
#pragma unroll
        for (int n = 0; n < kN; n++) {
            float mr = m[n].x, mi = m[n].y;
            m[n] = mkv2(__builtin_fmaf(mr, mr, -(mi * mi)), 2.0f * mr * mi);
        }
        __syncthreads();                 // writes visible for next step
    }

    // --- final state (inclusive prefix of row 127) -> hout, h = p*u
    if (tid < kN) {
        int n = tid;
        float4 t = scan4[127 * 8 + ((n >> 1) ^ 7)];
        float Hr = (n & 1) ? t.z : t.x;
        float Hi = (n & 1) ? t.w : t.y;
        hout[(size_t)(row * kN + n) * 2 + 0] = cp[n] * Hr;
        hout[(size_t)(row * kN + n) * 2 + 1] = cp[n] * Hi;
    }

    // --- exclusive prefix = inclusive of thread tid-1 -> phase-3 init
    if (tid == 0) {
#pragma unroll
        for (int n = 0; n < kN; n++) u[n] = mkv2(0.0f, 0.0f);
    } else {
        int r = tid - 1, rsw = r & 7;
#pragma unroll
        for (int k = 0; k < 8; k++) {
            float4 t = scan4[r * 8 + (k ^ rsw)];
            u[2*k]   = mkv2(t.x, t.y);
            u[2*k+1] = mkv2(t.z, t.w);
        }
    }

    // --- rebuild coefficient registers from LDS (they were dead during the
    //     scan; re-reading here keeps peak scan-region liveness low).
    v2 g[kN];
#pragma unroll
    for (int n = 0; n < kN; n++) {
        qx[n] = mkv2(cqr[n],  cqr[n]);
        qy[n] = mkv2(-cqi[n], cqi[n]);
        g[n]  = mkv2(cgr[n],  cgi[n]);
    }
    const float om = omega[d];

    // --- phase 3: re-run chunk from correct init, emit y
    float ys[kCH];
#pragma unroll
    for (int j = 0; j < kCH; j++) {
        v2 xv = mkv2(xs[j], 0.0f);
        v2 acc0 = mkv2(0.0f, 0.0f), acc1 = mkv2(0.0f, 0.0f);
        v2 acc2 = mkv2(0.0f, 0.0f), acc3 = mkv2(0.0f, 0.0f);
#pragma unroll
        for (int n = 0; n < kN; n += 4) {
            v2 a;
            a = v2fma(qx[n],   u[n],   xv);
            u[n]   = v2fma(qy[n],   mkv2(u[n].y,   u[n].x),   a);
            acc0   = v2fma(g[n],    u[n],   acc0);
            a = v2fma(qx[n+1], u[n+1], xv);
            u[n+1] = v2fma(qy[n+1], mkv2(u[n+1].y, u[n+1].x), a);
            acc1   = v2fma(g[n+1],  u[n+1], acc1);
            a = v2fma(qx[n+2], u[n+2], xv);
            u[n+2] = v2fma(qy[n+2], mkv2(u[n+2].y, u[n+2].x), a);
            acc2   = v2fma(g[n+2],  u[n+2], acc2);
            a = v2fma(qx[n+3], u[n+3], xv);
            u[n+3] = v2fma(qy[n+3], mkv2(u[n+3].y, u[n+3].x), a);
            acc3   = v2fma(g[n+3],  u[n+3], acc3);
        }
        v2 s = (acc0 + acc1) + (acc2 + acc3);
        ys[j] = s.x + s.y + om * xs[j];
    }

    // burst stores (8 back-to-back dwordx4 = 128 B/lane)
    float4* yp = (float4*)(y + (size_t)row * kL + (size_t)tid * kCH);
#pragma unroll
    for (int k = 0; k < 8; k++)
        yp[k] = make_float4(ys[4*k+0], ys[4*k+1], ys[4*k+2], ys[4*k+3]);
}

extern "C" void kernel_launch(void* const* d_in, const int* in_sizes, int n_in,
                              void* d_out, int out_size, void* d_ws, size_t ws_size,
                              hipStream_t stream) {
    const float* x     = (const float*)d_in[0];
    const float* alpha = (const float*)d_in[1];
    const float* delta = (const float*)d_in[2];
    const float* theta = (const float*)d_in[3];
    const float* gamma = (const float*)d_in[4];
    const float* omega = (const float*)d_in[5];
    float* y    = (float*)d_out;
    float* hout = y + (size_t)kB * kD * kL;      // (B,D,N,2) after y

    fused_kernel<<<kB * kD, kT, 0, stream>>>(x, alpha, delta, theta, gamma,
                                             omega, y, hout);
}